// Round 1
// baseline (916.053 us; speedup 1.0000x reference)
//
#include <hip/hip_runtime.h>

// SkipLSTM: B=256, T=784, I=1, H=110, NCLS=10
// One block per batch element (256 blocks == 256 CUs), 512 threads/block.
// Thread j (j<440) holds W_hh row j in registers (112 VGPRs incl. pad).
// Per step: gates via register MACs against broadcast h from LDS; gate
// activations round-trip through LDS; du reduction done redundantly per-wave.

#define T784 784
#define H110 110
#define G440 440
#define HP   112   // H padded to multiple of 16 (pad weights/h with zeros)
#define NT   512
#define NCLS 10

__device__ __forceinline__ float sigm(float x) {
    return 1.0f / (1.0f + __expf(-x));
}
__device__ __forceinline__ float ftanh(float x) {
    // tanh(x) = 1 - 2/(exp(2x)+1); saturates correctly at +/-inf
    float e = __expf(2.0f * x);
    return 1.0f - 2.0f / (e + 1.0f);
}

__global__ __launch_bounds__(NT, 1)
void skiplstm_kernel(const float* __restrict__ x,
                     const float* __restrict__ W_ih,
                     const float* __restrict__ W_hh,
                     const float* __restrict__ b,
                     const float* __restrict__ W_p,
                     const float* __restrict__ b_p,
                     const float* __restrict__ h0,
                     const float* __restrict__ c0,
                     const float* __restrict__ W_fc,
                     const float* __restrict__ b_fc,
                     float* __restrict__ out)
{
    __shared__ __align__(16) float s_h[HP];      // hidden state (broadcast source)
    __shared__ float s_act[G440];                // activated gates i|f|g|o
    __shared__ float s_p[128];                   // c_n * W_p partials (padded, zeros)
    __shared__ float s_wp[HP];
    __shared__ float s_x[T784];                  // this batch row of x
    __shared__ float s_stage[64 * H110];         // staging for coalesced W_hh load

    const int tid = threadIdx.x;
    const int bb  = blockIdx.x;

    // ---- load W_hh rows into registers via coalesced LDS staging ----
    float w[HP];
    w[110] = 0.0f; w[111] = 0.0f;
    for (int r0 = 0; r0 < G440; r0 += 64) {
        const int nrows = (G440 - r0) < 64 ? (G440 - r0) : 64;
        const int cnt = nrows * H110;
        for (int i = tid; i < cnt; i += NT)
            s_stage[i] = W_hh[r0 * H110 + i];    // coalesced
        __syncthreads();
        if (tid >= r0 && tid < r0 + nrows) {
            const int lr = tid - r0;
            #pragma unroll
            for (int k = 0; k < H110; k += 2) {  // 110 even, float2-aligned
                float2 v = *(const float2*)(s_stage + lr * H110 + k);
                w[k] = v.x; w[k + 1] = v.y;
            }
        }
        __syncthreads();
    }

    float wih = 0.0f, bias = 0.0f;
    if (tid < G440) { wih = W_ih[tid]; bias = b[tid]; }

    float hreg = 0.0f, creg = 0.0f;              // thread k<110 owns h[k], c[k]
    if (tid < HP) {
        float hv = (tid < H110) ? h0[tid] : 0.0f;
        s_h[tid]  = hv;
        s_wp[tid] = (tid < H110) ? W_p[tid] : 0.0f;
        if (tid < H110) { hreg = hv; creg = c0[tid]; }
    }
    if (tid < 128) s_p[tid] = 0.0f;
    for (int i = tid; i < T784; i += NT) s_x[i] = x[bb * T784 + i];
    const float bp = b_p[0];

    float u = 1.0f;                              // u0 = 1 -> first step updates
    int count = 0;
    __syncthreads();

    for (int t = 0; t < T784; ++t) {
        const float ub = rintf(u);               // round-half-even == jnp.round
        const bool  up = ub > 0.5f;
        count += up ? 1 : 0;
        const float xt = s_x[t];

        if (tid < G440) {
            float a0 = 0.f, a1 = 0.f, a2 = 0.f, a3 = 0.f;
            #pragma unroll
            for (int k = 0; k < HP; k += 16) {
                float4 hA = *(const float4*)(s_h + k);
                float4 hB = *(const float4*)(s_h + k + 4);
                float4 hC = *(const float4*)(s_h + k + 8);
                float4 hD = *(const float4*)(s_h + k + 12);
                a0 = fmaf(hA.x, w[k + 0], a0);
                a0 = fmaf(hA.y, w[k + 1], a0);
                a0 = fmaf(hA.z, w[k + 2], a0);
                a0 = fmaf(hA.w, w[k + 3], a0);
                a1 = fmaf(hB.x, w[k + 4], a1);
                a1 = fmaf(hB.y, w[k + 5], a1);
                a1 = fmaf(hB.z, w[k + 6], a1);
                a1 = fmaf(hB.w, w[k + 7], a1);
                a2 = fmaf(hC.x, w[k + 8], a2);
                a2 = fmaf(hC.y, w[k + 9], a2);
                a2 = fmaf(hC.z, w[k + 10], a2);
                a2 = fmaf(hC.w, w[k + 11], a2);
                a3 = fmaf(hD.x, w[k + 12], a3);
                a3 = fmaf(hD.y, w[k + 13], a3);
                a3 = fmaf(hD.z, w[k + 14], a3);
                a3 = fmaf(hD.w, w[k + 15], a3);
            }
            float acc = ((a0 + a1) + (a2 + a3)) + bias + xt * wih;
            const bool isg = (tid >= 2 * H110) && (tid < 3 * H110); // g-gate -> tanh
            s_act[tid] = isg ? ftanh(acc) : sigm(acc);
        }
        __syncthreads();                         // acts visible; s_h reads done

        if (tid < H110) {
            const float gi = s_act[tid];
            const float gf = s_act[tid + H110];
            const float gg = s_act[tid + 2 * H110];
            const float go = s_act[tid + 3 * H110];
            const float c_new = fmaf(gf, creg, gi * gg);
            const float h_new = go * ftanh(c_new);
            creg = up ? c_new : creg;            // ub is exactly 0/1 -> select
            hreg = up ? h_new : hreg;
            s_h[tid] = hreg;
            s_p[tid] = creg * s_wp[tid];
        }
        __syncthreads();                         // new h and p visible

        // redundant per-wave reduction of p[0..109] -> du (deterministic)
        const int lane = tid & 63;
        float v = s_p[lane] + s_p[lane + 64];
        #pragma unroll
        for (int off = 32; off > 0; off >>= 1)
            v += __shfl_xor(v, off, 64);
        const float du = sigm(v + bp);
        u = up ? du : (u + fminf(du, 1.0f - u));
    }

    // epilogue: out[bb,:] = h_last @ W_fc^T + b_fc
    if (tid < NCLS) {
        float acc = b_fc[tid];
        #pragma unroll 10
        for (int k = 0; k < H110; ++k)
            acc = fmaf(s_h[k], W_fc[tid * H110 + k], acc);
        out[bb * NCLS + tid] = acc;
    }
    if (tid == 0)
        atomicAdd(out + 256 * NCLS, (float)count);   // total_u at flat index 2560
}

__global__ void zero_tail_kernel(float* out) {
    if (threadIdx.x == 0) out[256 * NCLS] = 0.0f;    // d_out is poisoned 0xAA
}

extern "C" void kernel_launch(void* const* d_in, const int* in_sizes, int n_in,
                              void* d_out, int out_size, void* d_ws, size_t ws_size,
                              hipStream_t stream) {
    const float* x    = (const float*)d_in[0];
    const float* W_ih = (const float*)d_in[1];
    const float* W_hh = (const float*)d_in[2];
    const float* b    = (const float*)d_in[3];
    const float* W_p  = (const float*)d_in[4];
    const float* b_p  = (const float*)d_in[5];
    const float* h0   = (const float*)d_in[6];
    const float* c0   = (const float*)d_in[7];
    const float* W_fc = (const float*)d_in[8];
    const float* b_fc = (const float*)d_in[9];
    float* out = (float*)d_out;

    zero_tail_kernel<<<1, 64, 0, stream>>>(out);
    skiplstm_kernel<<<256, NT, 0, stream>>>(x, W_ih, W_hh, b, W_p, b_p,
                                            h0, c0, W_fc, b_fc, out);
}

// Round 2
// 706.798 us; speedup vs baseline: 1.2961x; 1.2961x over previous
//
#include <hip/hip_runtime.h>

// SkipLSTM: B=256, T=784, I=1, H=110, NCLS=10
// One block per batch element. 896 threads = 14 waves.
// 220 groups x 4 lanes: group g owns gate rows 2g, 2g+1; lane q holds
// weight cols [28q, 28q+28) of both rows -> 14 float4 = 56 VGPRs (true
// registers this time; round-1's 112-float array got AGPR-parked, costing
// ~770 extra VALU cyc/step in register moves).
// Quad-partial reduce via DPP quad_perm (VALU, no DS traffic).
// du-reduction runs in wave 0 only; broadcast via s_ub with barrier separation.

#define T784 784
#define H110 110
#define HP   112          // H padded to 112 (zeros)
#define G440 440
#define NGRP 220
#define NACT 880
#define NT   896
#define NCLS 10

__device__ __forceinline__ float sigm(float x) { return 1.0f / (1.0f + __expf(-x)); }
__device__ __forceinline__ float ftanh(float x) {
    float e = __expf(2.0f * x);
    return 1.0f - 2.0f / (e + 1.0f);
}
template <int CTRL>
__device__ __forceinline__ float dpp_qperm(float v) {
    // quad_perm cross-lane move on the VALU pipe (no DS)
    return __int_as_float(
        __builtin_amdgcn_update_dpp(0, __float_as_int(v), CTRL, 0xF, 0xF, true));
}

__global__ __launch_bounds__(NT, 1)
void skiplstm_kernel(const float* __restrict__ x,
                     const float* __restrict__ W_ih,
                     const float* __restrict__ W_hh,
                     const float* __restrict__ b,
                     const float* __restrict__ W_p,
                     const float* __restrict__ b_p,
                     const float* __restrict__ h0,
                     const float* __restrict__ c0,
                     const float* __restrict__ W_fc,
                     const float* __restrict__ b_fc,
                     float* __restrict__ out)
{
    __shared__ __align__(16) float s_h[HP];     // hidden state, broadcast source
    __shared__ float s_act[G440];               // activated gates i|f|g|o
    __shared__ float s_p[128];                  // c*W_p partials (110 live, pad 0)
    __shared__ float s_ub[1];                   // binarized update gate (scalar)
    __shared__ float s_x[T784];                 // this batch row of x
    __shared__ __align__(16) float s_stage[64 * HP];  // W_hh staging (padded rows)

    const int tid = threadIdx.x;
    const int bb  = blockIdx.x;
    const int g   = tid >> 2;       // row-pair group
    const int q   = tid & 3;        // col-slice lane
    const int rowA = 2 * g;
    const int rowB = 2 * g + 1;

    // ---- load weight slices into registers via padded LDS staging ----
    float4 wA[7], wB[7];
    #pragma unroll
    for (int j = 0; j < 7; ++j) { wA[j] = make_float4(0,0,0,0); wB[j] = make_float4(0,0,0,0); }

    for (int wnd = 0; wnd < 7; ++wnd) {
        const int r0 = wnd * 64;
        const int nr = (G440 - r0) < 64 ? (G440 - r0) : 64;
        const int cnt = nr * HP;
        for (int i = tid; i < cnt; i += NT) {
            const int r = i / HP, c = i - r * HP;
            s_stage[i] = (c < H110) ? W_hh[(r0 + r) * H110 + c] : 0.0f;
        }
        __syncthreads();
        if (g < NGRP && rowA >= r0 && rowA < r0 + nr) {
            const float4* st = (const float4*)s_stage;
            #pragma unroll
            for (int j = 0; j < 7; ++j) {
                wA[j] = st[(rowA - r0) * 28 + q * 7 + j];
                wB[j] = st[(rowB - r0) * 28 + q * 7 + j];
            }
        }
        __syncthreads();
    }

    // per-thread row constants (lane q writes row 2g + (q&1))
    const int  myrow = (g < NGRP) ? (rowA + (q & 1)) : 0;
    const float bias = (g < NGRP) ? b[myrow] : 0.0f;
    const float wih  = (g < NGRP) ? W_ih[myrow] : 0.0f;
    const bool  isg  = (myrow >= 2 * H110) && (myrow < 3 * H110);  // g-gate -> tanh
    const float bp   = b_p[0];

    float hreg = 0.0f, creg = 0.0f, wp = 0.0f;
    if (tid < 128) s_p[tid] = 0.0f;
    if (tid < HP) {
        float hv = (tid < H110) ? h0[tid] : 0.0f;
        s_h[tid] = hv;
        if (tid < H110) { hreg = hv; creg = c0[tid]; wp = W_p[tid]; }
    }
    if (tid == 0) s_ub[0] = 1.0f;               // u0 = 1 -> first step updates
    for (int i = tid; i < T784; i += NT) s_x[i] = x[bb * T784 + i];

    float u = 1.0f;                             // live only in wave 0
    int cnt_u = 0;                              // live only in thread 0
    __syncthreads();

    for (int t = 0; t < T784; ++t) {
        // ---- phase 1: gate pre-activations + activation ----
        if (tid < NACT) {
            const float xt = s_x[t];
            const float4* h4 = (const float4*)s_h;
            float a0 = 0.0f, a1 = 0.0f;
            #pragma unroll
            for (int j = 0; j < 7; ++j) {
                const float4 hv = h4[q * 7 + j];   // banks disjoint across q
                a0 = fmaf(hv.x, wA[j].x, a0); a0 = fmaf(hv.y, wA[j].y, a0);
                a0 = fmaf(hv.z, wA[j].z, a0); a0 = fmaf(hv.w, wA[j].w, a0);
                a1 = fmaf(hv.x, wB[j].x, a1); a1 = fmaf(hv.y, wB[j].y, a1);
                a1 = fmaf(hv.z, wB[j].z, a1); a1 = fmaf(hv.w, wB[j].w, a1);
            }
            // quad reduce over q via DPP (xor1 = [1,0,3,2], xor2 = [2,3,0,1])
            a0 += dpp_qperm<0xB1>(a0); a1 += dpp_qperm<0xB1>(a1);
            a0 += dpp_qperm<0x4E>(a0); a1 += dpp_qperm<0x4E>(a1);
            if (q < 2) {
                const float v = ((q == 0) ? a0 : a1) + bias + xt * wih;
                s_act[myrow] = isg ? ftanh(v) : sigm(v);
            }
        }
        __syncthreads();

        // ---- phase 2: cell/hidden update (110 threads) ----
        if (tid < H110) {
            const float ubv = s_ub[0];
            const bool  up  = ubv > 0.5f;
            const float gi = s_act[tid];
            const float gf = s_act[tid + H110];
            const float gg = s_act[tid + 2 * H110];
            const float go = s_act[tid + 3 * H110];
            const float c_new = fmaf(gf, creg, gi * gg);
            const float h_new = go * ftanh(c_new);
            creg = up ? c_new : creg;           // ub is exactly 0/1
            hreg = up ? h_new : hreg;
            s_h[tid] = hreg;
            s_p[tid] = creg * wp;
            if (tid == 0) cnt_u += up ? 1 : 0;
        }
        __syncthreads();

        // ---- phase 3: du reduction, wave 0 only ----
        // s_ub written here is read in phase 2 of step t+1 (barrier1 separates);
        // phase 1 of t+1 touches neither s_p nor s_ub, so no barrier needed here.
        if (tid < 64) {
            float v = s_p[tid] + s_p[tid + 64];
            #pragma unroll
            for (int off = 32; off; off >>= 1) v += __shfl_xor(v, off, 64);
            const float du = sigm(v + bp);
            const float ubw = rintf(u);         // == value phase 2 just consumed
            u = (ubw > 0.5f) ? du : (u + fminf(du, 1.0f - u));
            s_ub[0] = rintf(u);                 // round-half-even == jnp.round
        }
    }

    // ---- epilogue: out[bb,:] = h_last @ W_fc^T + b_fc ----
    if (tid < NCLS) {
        float acc = b_fc[tid];
        for (int k = 0; k < H110; ++k)
            acc = fmaf(s_h[k], W_fc[tid * H110 + k], acc);
        out[bb * NCLS + tid] = acc;
    }
    if (tid == 0)
        atomicAdd(out + 256 * NCLS, (float)cnt_u);   // total_u at flat index 2560
}

__global__ void zero_tail_kernel(float* out) {
    if (threadIdx.x == 0) out[256 * NCLS] = 0.0f;    // d_out is poisoned 0xAA
}

extern "C" void kernel_launch(void* const* d_in, const int* in_sizes, int n_in,
                              void* d_out, int out_size, void* d_ws, size_t ws_size,
                              hipStream_t stream) {
    const float* x    = (const float*)d_in[0];
    const float* W_ih = (const float*)d_in[1];
    const float* W_hh = (const float*)d_in[2];
    const float* b    = (const float*)d_in[3];
    const float* W_p  = (const float*)d_in[4];
    const float* b_p  = (const float*)d_in[5];
    const float* h0   = (const float*)d_in[6];
    const float* c0   = (const float*)d_in[7];
    const float* W_fc = (const float*)d_in[8];
    const float* b_fc = (const float*)d_in[9];
    float* out = (float*)d_out;

    zero_tail_kernel<<<1, 64, 0, stream>>>(out);
    skiplstm_kernel<<<256, NT, 0, stream>>>(x, W_ih, W_hh, b, W_p, b_p,
                                            h0, c0, W_fc, b_fc, out);
}